// Round 7
// baseline (47.126 us; speedup 1.0000x reference)
//
#include <hip/hip_runtime.h>
#include <math.h>
#include <float.h>

#define B_ 2
#define NQ 1024
#define NO 1024
#define LAT 128
#define NHEADS 4
#define RADIUS_ 0.5f
#define LN_EPS_ 1e-5f
#define PW_STRIDE 68   // floats per (wave,head) p-row; 68*4=272B, 16B-aligned, odd banks

#define V_BYTES ((size_t)B_ * NO * LAT * 4)

__device__ __forceinline__ float selh(int h, float a, float b, float c, float d) {
  return h == 0 ? a : (h == 1 ? b : (h == 2 ? c : d));
}

// ---------------- prep: v = LayerNorm(h_obs) @ Wv + bv, 4 rows/block -------
__global__ __launch_bounds__(256) void gano_prep_kernel(
    const float* __restrict__ h_obs, const float* __restrict__ ln_g,
    const float* __restrict__ ln_b, const float* __restrict__ Wv,
    const float* __restrict__ bv, float* __restrict__ v_out)
{
  const int tid = threadIdx.x;
  const int j = tid & 127;
  const int half = tid >> 7;
  const int wave = tid >> 6;
  const int lane = tid & 63;
  const int r0 = blockIdx.x * 4 + half * 2;

  __shared__ float s_redA[2][4];
  __shared__ float s_redB[2][4];
  __shared__ __align__(16) float s_hn[4][LAT];

  const float x0 = h_obs[(size_t)r0 * LAT + j];
  const float x1 = h_obs[(size_t)(r0 + 1) * LAT + j];
  float s0 = x0, s1 = x1;
  #pragma unroll
  for (int off = 32; off >= 1; off >>= 1) {
    s0 += __shfl_down(s0, off);
    s1 += __shfl_down(s1, off);
  }
  if (lane == 0) { s_redA[0][wave] = s0; s_redA[1][wave] = s1; }
  __syncthreads();
  const float mu0 = (s_redA[0][half * 2] + s_redA[0][half * 2 + 1]) * (1.0f / LAT);
  const float mu1 = (s_redA[1][half * 2] + s_redA[1][half * 2 + 1]) * (1.0f / LAT);
  const float d0 = x0 - mu0, d1 = x1 - mu1;
  float q0 = d0 * d0, q1 = d1 * d1;
  #pragma unroll
  for (int off = 32; off >= 1; off >>= 1) {
    q0 += __shfl_down(q0, off);
    q1 += __shfl_down(q1, off);
  }
  if (lane == 0) { s_redB[0][wave] = q0; s_redB[1][wave] = q1; }
  __syncthreads();
  const float var0 = (s_redB[0][half * 2] + s_redB[0][half * 2 + 1]) * (1.0f / LAT);
  const float var1 = (s_redB[1][half * 2] + s_redB[1][half * 2 + 1]) * (1.0f / LAT);
  const float g = ln_g[j], be = ln_b[j];
  s_hn[half * 2 + 0][j] = d0 * rsqrtf(var0 + LN_EPS_) * g + be;
  s_hn[half * 2 + 1][j] = d1 * rsqrtf(var1 + LN_EPS_) * g + be;
  __syncthreads();

  float a0 = 0.0f, a1 = 0.0f;
  const float4* h0 = (const float4*)s_hn[half * 2 + 0];
  const float4* h1 = (const float4*)s_hn[half * 2 + 1];
  #pragma unroll 4
  for (int k4 = 0; k4 < LAT / 4; ++k4) {
    const float4 u0 = h0[k4];
    const float4 u1 = h1[k4];
    const float w0 = Wv[(k4 * 4 + 0) * LAT + j];
    const float w1 = Wv[(k4 * 4 + 1) * LAT + j];
    const float w2 = Wv[(k4 * 4 + 2) * LAT + j];
    const float w3 = Wv[(k4 * 4 + 3) * LAT + j];
    a0 = fmaf(u0.x, w0, a0); a0 = fmaf(u0.y, w1, a0);
    a0 = fmaf(u0.z, w2, a0); a0 = fmaf(u0.w, w3, a0);
    a1 = fmaf(u1.x, w0, a1); a1 = fmaf(u1.y, w1, a1);
    a1 = fmaf(u1.z, w2, a1); a1 = fmaf(u1.w, w3, a1);
  }
  const float bvj = bv[j];
  v_out[(size_t)(r0 + 0) * LAT + j] = a0 + bvj;
  v_out[(size_t)(r0 + 1) * LAT + j] = a1 + bvj;
}

// ---------------- main: one block = one (b,q); wave-autonomous flash -------
__global__ __launch_bounds__(256, 6) void gano_main_kernel(
    const float* __restrict__ pos_obs, const float* __restrict__ pos_query,
    const int* __restrict__ obs_mask,
    const float* __restrict__ W1, const float* __restrict__ b1,
    const float* __restrict__ W2, const float* __restrict__ b2,
    const float* __restrict__ v, float* __restrict__ out)
{
  __shared__ int   s_vidx[NO];                         // 4 KB
  __shared__ float s_vdist[NO];                        // 4 KB
  __shared__ __align__(16) float s_w[LAT][8];          // 4 KB: C0,C1,C2,w9,W2[0..3]
  __shared__ __align__(16) float s_Q[LAT];             // 512 B
  __shared__ __align__(16) float s_pw[4][NHEADS][PW_STRIDE]; // 4.25 KB, wave-private p
  __shared__ float s_mz[4][2][NHEADS];                 // per-wave m, Z
  __shared__ int   s_cnt[16];

  const int tid = threadIdx.x;
  const int wave = tid >> 6, lane = tid & 63;
  const int bid = blockIdx.x;
  const int b = bid >> 10, q = bid & (NQ - 1);

  const float qx = pos_query[((size_t)b * NQ + q) * 3 + 0];
  const float qy = pos_query[((size_t)b * NQ + q) * 3 + 1];
  const float qz = pos_query[((size_t)b * NQ + q) * 3 + 2];

  // ---- stage derived weights + per-query Q row (coalesced W1 reads) ----
  if (tid < LAT) {
    const int j = tid;
    float w[10];
    #pragma unroll
    for (int k = 0; k < 10; ++k) w[k] = W1[k * LAT + j];
    s_w[j][0] = w[3] - w[6];
    s_w[j][1] = w[4] - w[7];
    s_w[j][2] = w[5] - w[8];
    s_w[j][3] = w[9];
    const float4 w2r = *(const float4*)&W2[j * NHEADS];
    s_w[j][4] = w2r.x; s_w[j][5] = w2r.y; s_w[j][6] = w2r.z; s_w[j][7] = w2r.w;
    s_Q[j] = b1[j] + qx * (w[0] + w[6]) + qy * (w[1] + w[7]) + qz * (w[2] + w[8]);
  }

  // ---- compaction of valid obs (2 barriers) ----
  const float* pob = pos_obs + (size_t)b * NO * 3;
  const int*   om  = obs_mask + (size_t)b * NO;
  float dists[4];
  unsigned long long bals[4];
  #pragma unroll
  for (int rd = 0; rd < 4; ++rd) {
    const int o = (rd << 8) + tid;
    const float ox = pob[o * 3 + 0], oy = pob[o * 3 + 1], oz = pob[o * 3 + 2];
    const float rx = qx - ox, ry = qy - oy, rz = qz - oz;
    const float dist = sqrtf(rx * rx + ry * ry + rz * rz);
    const int ok = (om[o] != 0) && (dist <= RADIUS_);
    const unsigned long long bal = __ballot(ok);
    if (lane == 0) s_cnt[(rd << 2) + wave] = __popcll(bal);
    bals[rd] = bal;
    dists[rd] = dist;
  }
  __syncthreads();
  int Nv = 0;
  #pragma unroll
  for (int k = 0; k < 16; ++k) Nv += s_cnt[k];
  #pragma unroll
  for (int rd = 0; rd < 4; ++rd) {
    const int slot = (rd << 2) + wave;
    int base = 0;
    for (int k = 0; k < slot; ++k) base += s_cnt[k];
    if ((bals[rd] >> lane) & 1ull) {
      const int pos = base + __popcll(bals[rd] & ((1ull << lane) - 1ull));
      s_vidx[pos] = (rd << 8) + tid;
      s_vdist[pos] = dists[rd];
    }
  }
  __syncthreads();   // also publishes s_w / s_Q

  // ---- wave-autonomous flash over this wave's item slice ----
  const int c0 = lane << 1;          // this lane owns cols c0, c0+1
  const int hh = lane >> 4;          // head of those cols
  const float* vbl = v + (size_t)b * NO * LAT + c0;
  const float b20 = b2[0], b21 = b2[1], b22 = b2[2], b23 = b2[3];

  float m0 = -FLT_MAX, m1 = -FLT_MAX, m2 = -FLT_MAX, m3 = -FLT_MAX;
  float z0 = 0.f, z1 = 0.f, z2 = 0.f, z3 = 0.f;
  float ax = 0.f, ay = 0.f;

  for (int cbase = wave << 6; cbase < Nv; cbase += 256) {
    const int cnt = min(64, Nv - cbase);
    const bool act = lane < cnt;
    const int slot = cbase + (act ? lane : (cnt - 1));
    const int idx = s_vidx[slot];
    const float dist = s_vdist[slot];
    const float ox = pob[idx * 3 + 0], oy = pob[idx * 3 + 1], oz = pob[idx * 3 + 2];

    // MLP: 128-j loop, weights broadcast from LDS
    float a0 = b20, a1 = b21, a2 = b22, a3 = b23;
    #pragma unroll 2
    for (int j4 = 0; j4 < LAT / 4; ++j4) {
      const float4 q4 = *(const float4*)&s_Q[j4 << 2];
      #pragma unroll
      for (int u = 0; u < 4; ++u) {
        const int j = (j4 << 2) + u;
        const float4 cw = *(const float4*)&s_w[j][0];
        const float4 w2 = *(const float4*)&s_w[j][4];
        const float qj = (u == 0) ? q4.x : (u == 1) ? q4.y : (u == 2) ? q4.z : q4.w;
        float gg = fmaf(cw.x, ox, qj);
        gg = fmaf(cw.y, oy, gg);
        gg = fmaf(cw.z, oz, gg);
        gg = fmaf(cw.w, dist, gg);
        gg = fmaxf(gg, 0.0f);
        a0 = fmaf(gg, w2.x, a0);
        a1 = fmaf(gg, w2.y, a1);
        a2 = fmaf(gg, w2.z, a2);
        a3 = fmaf(gg, w2.w, a3);
      }
    }
    const float l0 = act ? a0 : -FLT_MAX;
    const float l1 = act ? a1 : -FLT_MAX;
    const float l2 = act ? a2 : -FLT_MAX;
    const float l3 = act ? a3 : -FLT_MAX;

    // wave-private per-head chunk max (shfl-only, no barriers)
    float x0 = l0, x1 = l1, x2 = l2, x3 = l3;
    #pragma unroll
    for (int off = 1; off < 64; off <<= 1) {
      x0 = fmaxf(x0, __shfl_xor(x0, off));
      x1 = fmaxf(x1, __shfl_xor(x1, off));
      x2 = fmaxf(x2, __shfl_xor(x2, off));
      x3 = fmaxf(x3, __shfl_xor(x3, off));
    }
    const float nm0 = fmaxf(m0, x0), nm1 = fmaxf(m1, x1);
    const float nm2 = fmaxf(m2, x2), nm3 = fmaxf(m3, x3);
    const float sc0 = __expf(m0 - nm0), sc1 = __expf(m1 - nm1);
    const float sc2 = __expf(m2 - nm2), sc3 = __expf(m3 - nm3);
    m0 = nm0; m1 = nm1; m2 = nm2; m3 = nm3;

    const float p0 = __expf(l0 - nm0);
    const float p1 = __expf(l1 - nm1);
    const float p2 = __expf(l2 - nm2);
    const float p3 = __expf(l3 - nm3);
    s_pw[wave][0][lane] = p0;
    s_pw[wave][1][lane] = p1;
    s_pw[wave][2][lane] = p2;
    s_pw[wave][3][lane] = p3;
    z0 = z0 * sc0 + p0;
    z1 = z1 * sc1 + p1;
    z2 = z2 * sc2 + p2;
    z3 = z3 * sc3 + p3;
    const float sch = selh(hh, sc0, sc1, sc2, sc3);
    ax *= sch; ay *= sch;

    // PV over this chunk (wave-private; compiler inserts lgkmcnt wait)
    const float* pr = s_pw[wave][hh];
    for (int it = 0; it < cnt; it += 4) {
      const float4 pq = *(const float4*)&pr[it];
      const int4 iq = *(const int4*)&s_vidx[cbase + it];
      const int i0 = iq.x & (NO - 1), i1 = iq.y & (NO - 1);
      const int i2 = iq.z & (NO - 1), i3 = iq.w & (NO - 1);
      const float2 v0 = *(const float2*)(vbl + (size_t)i0 * LAT);
      const float2 v1 = *(const float2*)(vbl + (size_t)i1 * LAT);
      const float2 v2 = *(const float2*)(vbl + (size_t)i2 * LAT);
      const float2 v3 = *(const float2*)(vbl + (size_t)i3 * LAT);
      ax = fmaf(pq.x, v0.x, ax); ay = fmaf(pq.x, v0.y, ay);
      ax = fmaf(pq.y, v1.x, ax); ay = fmaf(pq.y, v1.y, ay);
      ax = fmaf(pq.z, v2.x, ax); ay = fmaf(pq.z, v2.y, ay);
      ax = fmaf(pq.w, v3.x, ax); ay = fmaf(pq.w, v3.y, ay);
    }
  }

  // ---- per-wave epilogue: reduce Z, publish m/Z/partial ----
  #pragma unroll
  for (int off = 1; off < 64; off <<= 1) {
    z0 += __shfl_xor(z0, off);
    z1 += __shfl_xor(z1, off);
    z2 += __shfl_xor(z2, off);
    z3 += __shfl_xor(z3, off);
  }
  if (lane == 0) {
    s_mz[wave][0][0] = m0; s_mz[wave][0][1] = m1;
    s_mz[wave][0][2] = m2; s_mz[wave][0][3] = m3;
    s_mz[wave][1][0] = z0; s_mz[wave][1][1] = z1;
    s_mz[wave][1][2] = z2; s_mz[wave][1][3] = z3;
  }
  // reuse this wave's (now dead) p-buffer for the PV partial
  float* part = &s_pw[wave][0][0];
  part[c0] = ax; part[c0 + 1] = ay;
  __syncthreads();

  // ---- combine 4 wave-partials ----
  if (tid < LAT) {
    const int h = tid >> 5;
    const float mw0 = s_mz[0][0][h], mw1 = s_mz[1][0][h];
    const float mw2 = s_mz[2][0][h], mw3 = s_mz[3][0][h];
    const float M = fmaxf(fmaxf(mw0, mw1), fmaxf(mw2, mw3));
    float num = 0.f, den = 0.f;
    #pragma unroll
    for (int w = 0; w < 4; ++w) {
      const float e = __expf(s_mz[w][0][h] - M);
      num = fmaf(e, (&s_pw[w][0][0])[tid], num);
      den = fmaf(e, s_mz[w][1][h], den);
    }
    const float r = (Nv > 0) ? (num / den) : 0.0f;
    out[((size_t)b * NQ + q) * LAT + tid] = r;
  }
}

extern "C" void kernel_launch(void* const* d_in, const int* in_sizes, int n_in,
                              void* d_out, int out_size, void* d_ws, size_t ws_size,
                              hipStream_t stream) {
  const float* h_obs     = (const float*)d_in[0];
  const float* pos_obs   = (const float*)d_in[1];
  const float* pos_query = (const float*)d_in[2];
  const int*   obs_mask  = (const int*)d_in[3];
  const float* W1        = (const float*)d_in[4];
  const float* b1        = (const float*)d_in[5];
  const float* W2        = (const float*)d_in[6];
  const float* b2        = (const float*)d_in[7];
  const float* ln_g      = (const float*)d_in[8];
  const float* ln_b      = (const float*)d_in[9];
  const float* Wv        = (const float*)d_in[10];
  const float* bv        = (const float*)d_in[11];
  float* outp = (float*)d_out;
  float* v    = (float*)d_ws;   // 1 MB

  gano_prep_kernel<<<(B_ * NO) / 4, 256, 0, stream>>>(h_obs, ln_g, ln_b, Wv, bv, v);
  gano_main_kernel<<<B_ * NQ, 256, 0, stream>>>(pos_obs, pos_query, obs_mask,
                                                W1, b1, W2, b2, v, outp);
}

// Round 8
// 44.594 us; speedup vs baseline: 1.0568x; 1.0568x over previous
//
#include <hip/hip_runtime.h>
#include <math.h>
#include <float.h>

#define B_ 2
#define NQ 1024
#define NO 1024
#define LAT 128
#define NHEADS 4
#define RADIUS_ 0.5f
#define LN_EPS_ 1e-5f
#define CAP 256          // items buffered per pass (4 slots x 64 lanes)
#define PPAD 264         // s_p head stride: 264%32=8 -> heads land on banks 0/8/16/24

#define V_BYTES ((size_t)B_ * NO * LAT * 4)

__device__ __forceinline__ float selh(int h, float a, float b, float c, float d) {
  return h == 0 ? a : (h == 1 ? b : (h == 2 ? c : d));
}

// workspace: v (B*NO*LAT f32) | A4 (LAT float4) | CW8 (2*LAT float4)
// A4[j]     = (W1[0]+W1[6], W1[1]+W1[7], W1[2]+W1[8], b1[j])
// CW8[2j]   = (W1[3]-W1[6], W1[4]-W1[7], W1[5]-W1[8], W1[9]) col j
// CW8[2j+1] = W2[j][0..3]

// ---------------- prep: v = LayerNorm(h_obs) @ Wv + bv, 4 rows/block -------
__global__ __launch_bounds__(256) void gano_prep_kernel(
    const float* __restrict__ h_obs, const float* __restrict__ ln_g,
    const float* __restrict__ ln_b, const float* __restrict__ Wv,
    const float* __restrict__ bv, const float* __restrict__ W1,
    const float* __restrict__ b1, const float* __restrict__ W2,
    float* __restrict__ v_out,
    float4* __restrict__ A4, float4* __restrict__ CW8, int write_derived)
{
  const int tid = threadIdx.x;
  const int j = tid & 127;
  const int half = tid >> 7;
  const int wave = tid >> 6;
  const int lane = tid & 63;
  const int r0 = blockIdx.x * 4 + half * 2;

  __shared__ float s_redA[2][4];
  __shared__ float s_redB[2][4];
  __shared__ __align__(16) float s_hn[4][LAT];

  const float x0 = h_obs[(size_t)r0 * LAT + j];
  const float x1 = h_obs[(size_t)(r0 + 1) * LAT + j];
  float s0 = x0, s1 = x1;
  #pragma unroll
  for (int off = 32; off >= 1; off >>= 1) {
    s0 += __shfl_down(s0, off);
    s1 += __shfl_down(s1, off);
  }
  if (lane == 0) { s_redA[0][wave] = s0; s_redA[1][wave] = s1; }
  __syncthreads();
  const float mu0 = (s_redA[0][half * 2] + s_redA[0][half * 2 + 1]) * (1.0f / LAT);
  const float mu1 = (s_redA[1][half * 2] + s_redA[1][half * 2 + 1]) * (1.0f / LAT);
  const float d0 = x0 - mu0, d1 = x1 - mu1;
  float q0 = d0 * d0, q1 = d1 * d1;
  #pragma unroll
  for (int off = 32; off >= 1; off >>= 1) {
    q0 += __shfl_down(q0, off);
    q1 += __shfl_down(q1, off);
  }
  if (lane == 0) { s_redB[0][wave] = q0; s_redB[1][wave] = q1; }
  __syncthreads();
  const float var0 = (s_redB[0][half * 2] + s_redB[0][half * 2 + 1]) * (1.0f / LAT);
  const float var1 = (s_redB[1][half * 2] + s_redB[1][half * 2 + 1]) * (1.0f / LAT);
  const float g = ln_g[j], be = ln_b[j];
  s_hn[half * 2 + 0][j] = d0 * rsqrtf(var0 + LN_EPS_) * g + be;
  s_hn[half * 2 + 1][j] = d1 * rsqrtf(var1 + LN_EPS_) * g + be;
  __syncthreads();

  float a0 = 0.0f, a1 = 0.0f;
  const float4* h0 = (const float4*)s_hn[half * 2 + 0];
  const float4* h1 = (const float4*)s_hn[half * 2 + 1];
  #pragma unroll 4
  for (int k4 = 0; k4 < LAT / 4; ++k4) {
    const float4 u0 = h0[k4];
    const float4 u1 = h1[k4];
    const float w0 = Wv[(k4 * 4 + 0) * LAT + j];
    const float w1 = Wv[(k4 * 4 + 1) * LAT + j];
    const float w2 = Wv[(k4 * 4 + 2) * LAT + j];
    const float w3 = Wv[(k4 * 4 + 3) * LAT + j];
    a0 = fmaf(u0.x, w0, a0); a0 = fmaf(u0.y, w1, a0);
    a0 = fmaf(u0.z, w2, a0); a0 = fmaf(u0.w, w3, a0);
    a1 = fmaf(u1.x, w0, a1); a1 = fmaf(u1.y, w1, a1);
    a1 = fmaf(u1.z, w2, a1); a1 = fmaf(u1.w, w3, a1);
  }
  const float bvj = bv[j];
  v_out[(size_t)(r0 + 0) * LAT + j] = a0 + bvj;
  v_out[(size_t)(r0 + 1) * LAT + j] = a1 + bvj;

  if (write_derived && blockIdx.x == 0 && tid < LAT) {
    float w[10];
    #pragma unroll
    for (int k = 0; k < 10; ++k) w[k] = W1[k * LAT + tid];
    A4[tid] = make_float4(w[0] + w[6], w[1] + w[7], w[2] + w[8], b1[tid]);
    CW8[2 * tid + 0] = make_float4(w[3] - w[6], w[4] - w[7], w[5] - w[8], w[9]);
    CW8[2 * tid + 1] = make_float4(W2[tid * NHEADS + 0], W2[tid * NHEADS + 1],
                                   W2[tid * NHEADS + 2], W2[tid * NHEADS + 3]);
  }
}

// ---------------- flash pass over <=256 buffered items (one wave) ----------
template <int NS, bool DERIVED>
__device__ __forceinline__ void flash_pass(
    int lane, int cnt,
    const float4* __restrict__ s_list_w, const int* __restrict__ s_idx_w,
    const float* __restrict__ s_Qw, float* __restrict__ s_pw,
    const float4* __restrict__ CW8,
    const float* __restrict__ W1, const float* __restrict__ W2,
    float b20, float b21, float b22, float b23,
    const float* __restrict__ vb, int hh,
    float& m0, float& m1, float& m2, float& m3,
    float& z0, float& z1, float& z2, float& z3,
    float& ax, float& ay)
{
  float4 C[NS];
  bool act[NS];
  #pragma unroll
  for (int r = 0; r < NS; ++r) {
    const int s = r * 64 + lane;
    act[r] = s < cnt;
    C[r] = s_list_w[act[r] ? s : (cnt - 1)];
  }
  float L[NS][NHEADS];
  #pragma unroll
  for (int r = 0; r < NS; ++r) {
    L[r][0] = b20; L[r][1] = b21; L[r][2] = b22; L[r][3] = b23;
  }

  // MLP: weights via wave-uniform global reads (scalar pipe), q via LDS bcast
  #pragma unroll 2
  for (int j4 = 0; j4 < LAT / 4; ++j4) {
    const float4 q4 = *(const float4*)&s_Qw[j4 << 2];
    #pragma unroll
    for (int u = 0; u < 4; ++u) {
      const int j = (j4 << 2) + u;
      float4 cw, w2;
      if constexpr (DERIVED) {
        cw = CW8[2 * j + 0];
        w2 = CW8[2 * j + 1];
      } else {
        cw = make_float4(W1[3 * LAT + j] - W1[6 * LAT + j],
                         W1[4 * LAT + j] - W1[7 * LAT + j],
                         W1[5 * LAT + j] - W1[8 * LAT + j],
                         W1[9 * LAT + j]);
        w2 = *(const float4*)&W2[j * NHEADS];
      }
      const float qj = (u == 0) ? q4.x : (u == 1) ? q4.y : (u == 2) ? q4.z : q4.w;
      #pragma unroll
      for (int r = 0; r < NS; ++r) {
        float gg = fmaf(cw.x, C[r].x, qj);
        gg = fmaf(cw.y, C[r].y, gg);
        gg = fmaf(cw.z, C[r].z, gg);
        gg = fmaf(cw.w, C[r].w, gg);
        gg = fmaxf(gg, 0.0f);
        L[r][0] = fmaf(gg, w2.x, L[r][0]);
        L[r][1] = fmaf(gg, w2.y, L[r][1]);
        L[r][2] = fmaf(gg, w2.z, L[r][2]);
        L[r][3] = fmaf(gg, w2.w, L[r][3]);
      }
    }
  }
  #pragma unroll
  for (int r = 0; r < NS; ++r)
    if (!act[r]) { L[r][0] = L[r][1] = L[r][2] = L[r][3] = -FLT_MAX; }

  // chunk max per head (wave shfl, no barriers)
  float x0 = L[0][0], x1 = L[0][1], x2 = L[0][2], x3 = L[0][3];
  #pragma unroll
  for (int r = 1; r < NS; ++r) {
    x0 = fmaxf(x0, L[r][0]); x1 = fmaxf(x1, L[r][1]);
    x2 = fmaxf(x2, L[r][2]); x3 = fmaxf(x3, L[r][3]);
  }
  #pragma unroll
  for (int off = 1; off < 64; off <<= 1) {
    x0 = fmaxf(x0, __shfl_xor(x0, off));
    x1 = fmaxf(x1, __shfl_xor(x1, off));
    x2 = fmaxf(x2, __shfl_xor(x2, off));
    x3 = fmaxf(x3, __shfl_xor(x3, off));
  }
  const float nm0 = fmaxf(m0, x0), nm1 = fmaxf(m1, x1);
  const float nm2 = fmaxf(m2, x2), nm3 = fmaxf(m3, x3);
  const float sc0 = __expf(m0 - nm0), sc1 = __expf(m1 - nm1);
  const float sc2 = __expf(m2 - nm2), sc3 = __expf(m3 - nm3);
  m0 = nm0; m1 = nm1; m2 = nm2; m3 = nm3;

  // p = exp(l - m): inactive slots give exp(-inf) = 0 (natural padding)
  float pz0 = 0.f, pz1 = 0.f, pz2 = 0.f, pz3 = 0.f;
  #pragma unroll
  for (int r = 0; r < NS; ++r) {
    const float p0 = __expf(L[r][0] - nm0);
    const float p1 = __expf(L[r][1] - nm1);
    const float p2 = __expf(L[r][2] - nm2);
    const float p3 = __expf(L[r][3] - nm3);
    const int s = r * 64 + lane;
    s_pw[0 * PPAD + s] = p0;
    s_pw[1 * PPAD + s] = p1;
    s_pw[2 * PPAD + s] = p2;
    s_pw[3 * PPAD + s] = p3;
    pz0 += p0; pz1 += p1; pz2 += p2; pz3 += p3;
  }
  #pragma unroll
  for (int off = 1; off < 64; off <<= 1) {
    pz0 += __shfl_xor(pz0, off);
    pz1 += __shfl_xor(pz1, off);
    pz2 += __shfl_xor(pz2, off);
    pz3 += __shfl_xor(pz3, off);
  }
  z0 = z0 * sc0 + pz0;
  z1 = z1 * sc1 + pz1;
  z2 = z2 * sc2 + pz2;
  z3 = z3 * sc3 + pz3;

  // rescale running PV acc, then accumulate this pass
  const float sch = selh(hh, sc0, sc1, sc2, sc3);
  ax *= sch; ay *= sch;
  const float* pr = s_pw + hh * PPAD;
  #pragma unroll 2
  for (int it = 0; it < cnt; it += 4) {
    const float4 pq = *(const float4*)&pr[it];
    const int4 iq = *(const int4*)&s_idx_w[it];
    const float2 v0 = *(const float2*)(vb + (size_t)(iq.x & (NO - 1)) * LAT);
    const float2 v1 = *(const float2*)(vb + (size_t)(iq.y & (NO - 1)) * LAT);
    const float2 v2 = *(const float2*)(vb + (size_t)(iq.z & (NO - 1)) * LAT);
    const float2 v3 = *(const float2*)(vb + (size_t)(iq.w & (NO - 1)) * LAT);
    ax = fmaf(pq.x, v0.x, ax); ay = fmaf(pq.x, v0.y, ay);
    ax = fmaf(pq.y, v1.x, ax); ay = fmaf(pq.y, v1.y, ay);
    ax = fmaf(pq.z, v2.x, ax); ay = fmaf(pq.z, v2.y, ay);
    ax = fmaf(pq.w, v3.x, ax); ay = fmaf(pq.w, v3.y, ay);
  }
}

// ---------------- main: block = 4 queries, wave = 1 query, no barriers -----
template <bool DERIVED>
__global__ __launch_bounds__(256, 4) void gano_main_kernel(
    const float* __restrict__ pos_obs, const float* __restrict__ pos_query,
    const int* __restrict__ obs_mask,
    const float* __restrict__ W1, const float* __restrict__ b1,
    const float* __restrict__ W2, const float* __restrict__ b2,
    const float* __restrict__ v,
    const float4* __restrict__ A4, const float4* __restrict__ CW8,
    float* __restrict__ out)
{
  __shared__ __align__(16) float4 s_list[4][CAP];        // 16 KB
  __shared__ int   s_idx[4][CAP];                        // 4 KB
  __shared__ __align__(16) float s_p[4][NHEADS * PPAD];  // 16.5 KB
  __shared__ __align__(16) float s_Q[4][LAT];            // 2 KB

  const int tid = threadIdx.x;
  const int wave = tid >> 6, lane = tid & 63;
  const int qg = blockIdx.x * 4 + wave;         // global query 0..2047
  const int b = qg >> 10, q = qg & (NQ - 1);

  const float qx = pos_query[(size_t)qg * 3 + 0];
  const float qy = pos_query[(size_t)qg * 3 + 1];
  const float qz = pos_query[(size_t)qg * 3 + 2];

  // per-query Q row (wave-private staging, no barrier needed)
  #pragma unroll
  for (int jj = lane; jj < LAT; jj += 64) {
    float4 a;
    if constexpr (DERIVED) {
      a = A4[jj];
    } else {
      a = make_float4(W1[0 * LAT + jj] + W1[6 * LAT + jj],
                      W1[1 * LAT + jj] + W1[7 * LAT + jj],
                      W1[2 * LAT + jj] + W1[8 * LAT + jj],
                      b1[jj]);
    }
    s_Q[wave][jj] = fmaf(qx, a.x, fmaf(qy, a.y, fmaf(qz, a.z, a.w)));
  }

  const float* pob = pos_obs + (size_t)b * NO * 3;
  const int*   om  = obs_mask + (size_t)b * NO;
  const float b20 = b2[0], b21 = b2[1], b22 = b2[2], b23 = b2[3];
  const int c0 = lane << 1;
  const int hh = lane >> 4;
  const float* vb = v + (size_t)b * NO * LAT + c0;

  float m0 = -FLT_MAX, m1 = -FLT_MAX, m2 = -FLT_MAX, m3 = -FLT_MAX;
  float z0 = 0.f, z1 = 0.f, z2 = 0.f, z3 = 0.f;
  float ax = 0.f, ay = 0.f;

  const float4* listw = s_list[wave];
  const int*    idxw  = s_idx[wave];
  const float*  Qw    = s_Q[wave];
  float*        pw    = s_p[wave];

  int base = 0, nvtot = 0;

  #define RUN_PASS(N_)                                                        \
    flash_pass<N_, DERIVED>(lane, base, listw, idxw, Qw, pw, CW8, W1, W2,     \
                            b20, b21, b22, b23, vb, hh,                        \
                            m0, m1, m2, m3, z0, z1, z2, z3, ax, ay)
  #define DISPATCH_PASS()                                                     \
    do {                                                                      \
      const int ns_ = (base + 63) >> 6;                                       \
      if (ns_ == 4)      RUN_PASS(4);                                         \
      else if (ns_ == 3) RUN_PASS(3);                                         \
      else if (ns_ == 2) RUN_PASS(2);                                         \
      else               RUN_PASS(1);                                         \
    } while (0)

  for (int rd = 0; rd < 16; ++rd) {
    const int o = (rd << 6) + lane;
    const float ox = pob[o * 3 + 0], oy = pob[o * 3 + 1], oz = pob[o * 3 + 2];
    const float rx = qx - ox, ry = qy - oy, rz = qz - oz;
    const float dist = sqrtf(rx * rx + ry * ry + rz * rz);
    const int ok = (om[o] != 0) && (dist <= RADIUS_);
    const unsigned long long bal = __ballot(ok);
    const int cnt = __popcll(bal);
    if (base + cnt > CAP) {       // wave-uniform flush
      DISPATCH_PASS();
      base = 0;
    }
    if (ok) {
      const int pos = base + __popcll(bal & ((1ull << lane) - 1ull));
      s_list[wave][pos] = make_float4(ox, oy, oz, dist);
      s_idx[wave][pos] = o;
    }
    base += cnt;
    nvtot += cnt;
  }
  if (base > 0) DISPATCH_PASS();
  #undef RUN_PASS
  #undef DISPATCH_PASS

  // output: lane owns cols c0, c0+1 of its query
  const float zz = selh(hh, z0, z1, z2, z3);
  float2 o2;
  o2.x = (nvtot > 0) ? (ax / zz) : 0.0f;
  o2.y = (nvtot > 0) ? (ay / zz) : 0.0f;
  *(float2*)&out[(size_t)qg * LAT + c0] = o2;
}

extern "C" void kernel_launch(void* const* d_in, const int* in_sizes, int n_in,
                              void* d_out, int out_size, void* d_ws, size_t ws_size,
                              hipStream_t stream) {
  const float* h_obs     = (const float*)d_in[0];
  const float* pos_obs   = (const float*)d_in[1];
  const float* pos_query = (const float*)d_in[2];
  const int*   obs_mask  = (const int*)d_in[3];
  const float* W1        = (const float*)d_in[4];
  const float* b1        = (const float*)d_in[5];
  const float* W2        = (const float*)d_in[6];
  const float* b2        = (const float*)d_in[7];
  const float* ln_g      = (const float*)d_in[8];
  const float* ln_b      = (const float*)d_in[9];
  const float* Wv        = (const float*)d_in[10];
  const float* bv        = (const float*)d_in[11];
  float* outp = (float*)d_out;
  float* v    = (float*)d_ws;

  const size_t need = V_BYTES + 3 * LAT * sizeof(float4);
  const int derived = (ws_size >= need) ? 1 : 0;
  float4* A4  = (float4*)((char*)d_ws + V_BYTES);
  float4* CW8 = A4 + LAT;
  if (!derived) { A4 = (float4*)d_ws; CW8 = (float4*)d_ws; }

  gano_prep_kernel<<<(B_ * NO) / 4, 256, 0, stream>>>(h_obs, ln_g, ln_b, Wv, bv,
                                                      W1, b1, W2, v, A4, CW8, derived);
  if (derived) {
    gano_main_kernel<true><<<(B_ * NQ) / 4, 256, 0, stream>>>(
        pos_obs, pos_query, obs_mask, W1, b1, W2, b2, v,
        (const float4*)A4, (const float4*)CW8, outp);
  } else {
    gano_main_kernel<false><<<(B_ * NQ) / 4, 256, 0, stream>>>(
        pos_obs, pos_query, obs_mask, W1, b1, W2, b2, v,
        (const float4*)A4, (const float4*)CW8, outp);
  }
}